// Round 1
// baseline (771.163 us; speedup 1.0000x reference)
//
#include <hip/hip_runtime.h>

#define S_SIGMA 8
#define NBINS   16
#define HDIM    1024
#define WDIM    1024
#define GH      129   // (1024-1)/8 + 2
#define GW      129
#define GZ      17    // NBINS + 1
#define CELLS   (GH*GW*GZ)   // 282897 cells per image
#define EPSV    1e-8f

// grid stored as float2 (val, wt) interleaved
__global__ __launch_bounds__(256) void splat_kernel(
    const float* __restrict__ img, float* __restrict__ grid, int nImg, int imgBase)
{
    int total = nImg * HDIM * WDIM;
    for (int idx = blockIdx.x * blockDim.x + threadIdx.x; idx < total;
         idx += gridDim.x * blockDim.x) {
        int b   = idx / (HDIM * WDIM);
        int rem = idx - b * (HDIM * WDIM);
        int y   = rem / WDIM;
        int x   = rem - y * WDIM;
        float v = img[(size_t)(imgBase + b) * (HDIM * WDIM) + rem];
        // banker's rounding to match jnp.round exactly (ties at y = 8k+4)
        int gy = (int)rintf((float)y * 0.125f);
        int gx = (int)rintf((float)x * 0.125f);
        int gz = (int)rintf(v * 15.0f);
        gz = min(max(gz, 0), NBINS - 1);
        size_t cell = (((size_t)b * GH + gy) * GW + gx) * GZ + gz;
        atomicAdd(&grid[2 * cell],     v);
        atomicAdd(&grid[2 * cell + 1], 1.0f);
    }
}

// 5-tap correlation along AX (0=y,1=x,2=z) with zero padding.
template <int AX>
__global__ __launch_bounds__(256) void blur_kernel(
    const float2* __restrict__ in, float2* __restrict__ out,
    const float* __restrict__ kf, int nImg)
{
    float k0 = kf[0], k1 = kf[1], k2 = kf[2], k3 = kf[3], k4 = kf[4];
    float kk[5] = {k0, k1, k2, k3, k4};
    int total = nImg * CELLS;
    for (int idx = blockIdx.x * blockDim.x + threadIdx.x; idx < total;
         idx += gridDim.x * blockDim.x) {
        int b   = idx / CELLS;
        int rem = idx - b * CELLS;
        int y   = rem / (GW * GZ);
        int r2  = rem - y * (GW * GZ);
        int x   = r2 / GZ;
        int z   = r2 - x * GZ;

        int c      = (AX == 0) ? y  : (AX == 1) ? x  : z;
        int extent = (AX == 0) ? GH : (AX == 1) ? GW : GZ;
        int stride = (AX == 0) ? (GW * GZ) : (AX == 1) ? GZ : 1;

        float av = 0.f, aw = 0.f;
        #pragma unroll
        for (int t = 0; t < 5; ++t) {
            int cc = c + t - 2;
            if (cc >= 0 && cc < extent) {
                float2 g = in[idx + (cc - c) * stride];
                av += kk[t] * g.x;
                aw += kk[t] * g.y;
            }
        }
        float2 o; o.x = av; o.y = aw;
        out[idx] = o;
    }
}

__global__ __launch_bounds__(256) void slice_kernel(
    const float* __restrict__ img, const float2* __restrict__ grid,
    float* __restrict__ out, int nImg, int imgBase)
{
    int total = nImg * HDIM * WDIM;
    for (int idx = blockIdx.x * blockDim.x + threadIdx.x; idx < total;
         idx += gridDim.x * blockDim.x) {
        int b   = idx / (HDIM * WDIM);
        int rem = idx - b * (HDIM * WDIM);
        int y   = rem / WDIM;
        int x   = rem - y * WDIM;
        float v = img[(size_t)(imgBase + b) * (HDIM * WDIM) + rem];

        float fy = (float)y * 0.125f;
        float fx = (float)x * 0.125f;
        float fz = fminf(fmaxf(v * 15.0f, 0.0f), 15.0f);
        int y0 = (int)floorf(fy);
        int x0 = (int)floorf(fx);
        int z0 = (int)floorf(fz);
        int y1 = min(y0 + 1, GH - 1);
        int x1 = min(x0 + 1, GW - 1);
        int z1 = min(z0 + 1, GZ - 1);
        float ty = fy - (float)y0;
        float tx = fx - (float)x0;
        float tz = fz - (float)z0;

        const float2* gb = grid + (size_t)b * CELLS;
        float ov = 0.f, ow = 0.f;
        // match reference nesting order: y outer, x mid, z inner
        int   yis[2] = {y0, y1};     float wys[2] = {1.f - ty, ty};
        int   xis[2] = {x0, x1};     float wxs[2] = {1.f - tx, tx};
        int   zis[2] = {z0, z1};     float wzs[2] = {1.f - tz, tz};
        #pragma unroll
        for (int a = 0; a < 2; ++a) {
            #pragma unroll
            for (int c = 0; c < 2; ++c) {
                int base = (yis[a] * GW + xis[c]) * GZ;
                float wyx = wys[a] * wxs[c];
                #pragma unroll
                for (int d = 0; d < 2; ++d) {
                    float w = wyx * wzs[d];
                    float2 g = gb[base + zis[d]];
                    ov += w * g.x;
                    ow += w * g.y;
                }
            }
        }
        out[(size_t)(imgBase + b) * (HDIM * WDIM) + rem] = ov / (ow + EPSV);
    }
}

extern "C" void kernel_launch(void* const* d_in, const int* in_sizes, int n_in,
                              void* d_out, int out_size, void* d_ws, size_t ws_size,
                              hipStream_t stream)
{
    const float* img = (const float*)d_in[0];
    const float* fs  = (const float*)d_in[2];
    const float* fr  = (const float*)d_in[3];
    float* out = (float*)d_out;

    int nImgTotal = in_sizes[0] / (HDIM * WDIM);   // 12
    size_t perImgBytes = (size_t)CELLS * 2 * sizeof(float); // 2,263,176 B

    int maxChunk = (int)(ws_size / (2 * perImgBytes));
    if (maxChunk < 1) return;  // workspace too small — cannot run
    if (maxChunk > nImgTotal) maxChunk = nImgTotal;

    for (int base = 0; base < nImgTotal; base += maxChunk) {
        int c = nImgTotal - base;
        if (c > maxChunk) c = maxChunk;

        float* A = (float*)d_ws;                       // splat target / x-blur result
        float* B = A + (size_t)c * CELLS * 2;          // y-blur / z-blur result

        size_t bytesA = (size_t)c * perImgBytes;
        hipMemsetAsync(A, 0, bytesA, stream);

        int nPix = c * HDIM * WDIM;
        int pixBlocks = min((nPix + 255) / 256, 4096);
        splat_kernel<<<pixBlocks, 256, 0, stream>>>(img, A, c, base);

        int nCells = c * CELLS;
        int cellBlocks = min((nCells + 255) / 256, 4096);
        blur_kernel<0><<<cellBlocks, 256, 0, stream>>>((const float2*)A, (float2*)B, fs, c);
        blur_kernel<1><<<cellBlocks, 256, 0, stream>>>((const float2*)B, (float2*)A, fs, c);
        blur_kernel<2><<<cellBlocks, 256, 0, stream>>>((const float2*)A, (float2*)B, fr, c);

        slice_kernel<<<pixBlocks, 256, 0, stream>>>(img, (const float2*)B, out, c, base);
    }
}

// Round 2
// 260.452 us; speedup vs baseline: 2.9609x; 2.9609x over previous
//
#include <hip/hip_runtime.h>

#define S_SIGMA 8
#define NBINS   16
#define HDIM    1024
#define WDIM    1024
#define GH      129   // (1024-1)/8 + 2
#define GW      129
#define GZ      17    // NBINS + 1
#define CELLS   (GH*GW*GZ)   // 282897 cells per image
#define EPSV    1e-8f

// ---- LDS-privatized splat ----
// Each block: 64x64 pixel tile -> 9x9x16 local grid in LDS (gz only reaches 15).
#define LGY 9
#define LGX 9
#define LGZ 16
#define LCELLS (LGY*LGX*LGZ)   // 1296

__global__ __launch_bounds__(256) void splat_tile_kernel(
    const float* __restrict__ img, float* __restrict__ grid, int imgBase)
{
    __shared__ float lval[LCELLS];
    __shared__ float lwt [LCELLS];

    int tid = threadIdx.x;
    int tx = blockIdx.x;      // 0..15
    int ty = blockIdx.y;      // 0..15
    int b  = blockIdx.z;      // image within chunk

    for (int i = tid; i < LCELLS; i += 256) { lval[i] = 0.f; lwt[i] = 0.f; }
    __syncthreads();

    const float* ib = img + (size_t)(imgBase + b) * (HDIM * WDIM);
    int ybase = ty * 64, xbase = tx * 64;

    #pragma unroll
    for (int it = 0; it < 16; ++it) {
        int local = it * 256 + tid;
        int ly = local >> 6;
        int lx = local & 63;
        int y = ybase + ly, x = xbase + lx;
        float v = ib[y * WDIM + x];
        // banker's rounding matches jnp.round (ties at y = 8k+4, and v*15 == *.5)
        int gy = (int)rintf((float)y * 0.125f) - ty * 8;   // 0..8
        int gx = (int)rintf((float)x * 0.125f) - tx * 8;   // 0..8
        int gz = (int)rintf(v * 15.0f);
        gz = min(max(gz, 0), NBINS - 1);
        int c = (gy * LGX + gx) * LGZ + gz;
        atomicAdd(&lval[c], v);
        atomicAdd(&lwt[c], 1.0f);
    }
    __syncthreads();

    // flush non-empty cells to global grid (float2 interleaved) with atomics
    for (int i = tid; i < LCELLS; i += 256) {
        float w = lwt[i];
        if (w != 0.f) {
            int ly = i / (LGX * LGZ);
            int r  = i - ly * (LGX * LGZ);
            int lx = r / LGZ;
            int gz = r - lx * LGZ;
            int GY = ty * 8 + ly;
            int GX = tx * 8 + lx;
            size_t cell = (((size_t)b * GH + GY) * GW + GX) * GZ + gz;
            atomicAdd(&grid[2 * cell],     lval[i]);
            atomicAdd(&grid[2 * cell + 1], w);
        }
    }
}

// ---- blur along y, one thread per z-column ----
__global__ __launch_bounds__(256) void blur_y_col(
    const float2* __restrict__ in, float2* __restrict__ out,
    const float* __restrict__ kf, int nImg)
{
    int col = blockIdx.x * blockDim.x + threadIdx.x;
    int total = nImg * GH * GW;
    if (col >= total) return;
    int b   = col / (GH * GW);
    int rem = col - b * (GH * GW);
    int y   = rem / GW;

    float k0 = kf[0], k1 = kf[1], k2 = kf[2], k3 = kf[3], k4 = kf[4];
    float kk[5] = {k0, k1, k2, k3, k4};

    float2 acc[GZ];
    #pragma unroll
    for (int z = 0; z < GZ; ++z) { acc[z].x = 0.f; acc[z].y = 0.f; }

    #pragma unroll
    for (int t = 0; t < 5; ++t) {
        int yy = y + t - 2;
        if (yy >= 0 && yy < GH) {
            const float2* src = in + (size_t)(col + (t - 2) * GW) * GZ;
            float k = kk[t];
            #pragma unroll
            for (int z = 0; z < GZ; ++z) {
                float2 g = src[z];
                acc[z].x += k * g.x;
                acc[z].y += k * g.y;
            }
        }
    }
    float2* dst = out + (size_t)col * GZ;
    #pragma unroll
    for (int z = 0; z < GZ; ++z) dst[z] = acc[z];
}

// ---- fused blur along x then z, one thread per z-column ----
__global__ __launch_bounds__(256) void blur_xz_col(
    const float2* __restrict__ in, float2* __restrict__ out,
    const float* __restrict__ kfs, const float* __restrict__ kfr, int nImg)
{
    int col = blockIdx.x * blockDim.x + threadIdx.x;
    int total = nImg * GH * GW;
    if (col >= total) return;
    int b   = col / (GH * GW);
    int rem = col - b * (GH * GW);
    int x   = rem % GW;

    float ks[5] = {kfs[0], kfs[1], kfs[2], kfs[3], kfs[4]};
    float kr[5] = {kfr[0], kfr[1], kfr[2], kfr[3], kfr[4]};

    float2 tmp[GZ];
    #pragma unroll
    for (int z = 0; z < GZ; ++z) { tmp[z].x = 0.f; tmp[z].y = 0.f; }

    #pragma unroll
    for (int t = 0; t < 5; ++t) {
        int xx = x + t - 2;
        if (xx >= 0 && xx < GW) {
            const float2* src = in + (size_t)(col + (t - 2)) * GZ;
            float k = ks[t];
            #pragma unroll
            for (int z = 0; z < GZ; ++z) {
                float2 g = src[z];
                tmp[z].x += k * g.x;
                tmp[z].y += k * g.y;
            }
        }
    }
    // z blur in registers (zero pad)
    float2* dst = out + (size_t)col * GZ;
    #pragma unroll
    for (int z = 0; z < GZ; ++z) {
        float av = 0.f, aw = 0.f;
        #pragma unroll
        for (int t = 0; t < 5; ++t) {
            int zz = z + t - 2;
            if (zz >= 0 && zz < GZ) {
                av += kr[t] * tmp[zz].x;
                aw += kr[t] * tmp[zz].y;
            }
        }
        float2 o; o.x = av; o.y = aw;
        dst[z] = o;
    }
}

__global__ __launch_bounds__(256) void slice_kernel(
    const float* __restrict__ img, const float2* __restrict__ grid,
    float* __restrict__ out, int nImg, int imgBase)
{
    int total = nImg * HDIM * WDIM;
    for (int idx = blockIdx.x * blockDim.x + threadIdx.x; idx < total;
         idx += gridDim.x * blockDim.x) {
        int b   = idx / (HDIM * WDIM);
        int rem = idx - b * (HDIM * WDIM);
        int y   = rem / WDIM;
        int x   = rem - y * WDIM;
        float v = img[(size_t)(imgBase + b) * (HDIM * WDIM) + rem];

        float fy = (float)y * 0.125f;
        float fx = (float)x * 0.125f;
        float fz = fminf(fmaxf(v * 15.0f, 0.0f), 15.0f);
        int y0 = (int)floorf(fy);
        int x0 = (int)floorf(fx);
        int z0 = (int)floorf(fz);
        int y1 = min(y0 + 1, GH - 1);
        int x1 = min(x0 + 1, GW - 1);
        int z1 = min(z0 + 1, GZ - 1);
        float ty = fy - (float)y0;
        float tx = fx - (float)x0;
        float tz = fz - (float)z0;

        const float2* gb = grid + (size_t)b * CELLS;
        float ov = 0.f, ow = 0.f;
        int   yis[2] = {y0, y1};     float wys[2] = {1.f - ty, ty};
        int   xis[2] = {x0, x1};     float wxs[2] = {1.f - tx, tx};
        int   zis[2] = {z0, z1};     float wzs[2] = {1.f - tz, tz};
        #pragma unroll
        for (int a = 0; a < 2; ++a) {
            #pragma unroll
            for (int c = 0; c < 2; ++c) {
                int base = (yis[a] * GW + xis[c]) * GZ;
                float wyx = wys[a] * wxs[c];
                #pragma unroll
                for (int d = 0; d < 2; ++d) {
                    float w = wyx * wzs[d];
                    float2 g = gb[base + zis[d]];
                    ov += w * g.x;
                    ow += w * g.y;
                }
            }
        }
        out[(size_t)(imgBase + b) * (HDIM * WDIM) + rem] = ov / (ow + EPSV);
    }
}

extern "C" void kernel_launch(void* const* d_in, const int* in_sizes, int n_in,
                              void* d_out, int out_size, void* d_ws, size_t ws_size,
                              hipStream_t stream)
{
    const float* img = (const float*)d_in[0];
    const float* fs  = (const float*)d_in[2];
    const float* fr  = (const float*)d_in[3];
    float* out = (float*)d_out;

    int nImgTotal = in_sizes[0] / (HDIM * WDIM);   // 12
    size_t perImgBytes = (size_t)CELLS * 2 * sizeof(float);

    int maxChunk = (int)(ws_size / (2 * perImgBytes));
    if (maxChunk < 1) return;
    if (maxChunk > nImgTotal) maxChunk = nImgTotal;

    for (int base = 0; base < nImgTotal; base += maxChunk) {
        int c = nImgTotal - base;
        if (c > maxChunk) c = maxChunk;

        float* A = (float*)d_ws;
        float* B = A + (size_t)c * CELLS * 2;

        hipMemsetAsync(A, 0, (size_t)c * perImgBytes, stream);

        dim3 sgrid(16, 16, c);
        splat_tile_kernel<<<sgrid, 256, 0, stream>>>(img, A, base);

        int nCols = c * GH * GW;
        int colBlocks = (nCols + 255) / 256;
        blur_y_col <<<colBlocks, 256, 0, stream>>>((const float2*)A, (float2*)B, fs, c);
        blur_xz_col<<<colBlocks, 256, 0, stream>>>((const float2*)B, (float2*)A, fs, fr, c);

        int nPix = c * HDIM * WDIM;
        int pixBlocks = min((nPix + 255) / 256, 4096);
        slice_kernel<<<pixBlocks, 256, 0, stream>>>(img, (const float2*)A, out, c, base);
    }
}

// Round 3
// 157.472 us; speedup vs baseline: 4.8972x; 1.6540x over previous
//
#include <hip/hip_runtime.h>

#define S_SIGMA 8
#define NBINS   16
#define HDIM    1024
#define WDIM    1024
#define GH      129   // (1024-1)/8 + 2
#define GW      129
#define GZ      17    // NBINS + 1
#define CELLS   (GH*GW*GZ)   // 282897 cells per image
#define EPSV    1e-8f

// ---- gather splat: one thread per spatial cell (b,gy,gx), no atomics ----
// Banker's rounding footprint: even g -> [8g-4, 8g+4], odd g -> [8g-3, 8g+3].
__global__ __launch_bounds__(256) void splat_gather_kernel(
    const float* __restrict__ img, float* __restrict__ grid, int nImg, int imgBase)
{
    __shared__ float lval[16 * 256];   // [gz][tid] -> bank = tid%32, conflict-free
    __shared__ float lwt [16 * 256];

    int tid = threadIdx.x;
    int idx = blockIdx.x * blockDim.x + tid;
    int total = nImg * GH * GW;
    if (idx >= total) return;

    int b   = idx / (GH * GW);
    int rem = idx - b * (GH * GW);
    int gy  = rem / GW;
    int gx  = rem - gy * GW;

    #pragma unroll
    for (int z = 0; z < 16; ++z) { lval[z * 256 + tid] = 0.f; lwt[z * 256 + tid] = 0.f; }

    int ylo = max(0, 8 * gy - 4 + (gy & 1));
    int yhi = min(HDIM - 1, 8 * gy + 4 - (gy & 1));
    int xlo = max(0, 8 * gx - 4 + (gx & 1));
    int xhi = min(WDIM - 1, 8 * gx + 4 - (gx & 1));

    const float* ib = img + (size_t)(imgBase + b) * (HDIM * WDIM);
    for (int y = ylo; y <= yhi; ++y) {
        const float* row = ib + (size_t)y * WDIM;
        for (int x = xlo; x <= xhi; ++x) {
            float v = row[x];
            int gz = (int)rintf(v * 15.0f);      // banker's rounding = jnp.round
            gz = min(max(gz, 0), 15);
            lval[gz * 256 + tid] += v;
            lwt [gz * 256 + tid] += 1.0f;
        }
    }

    // write the cell's 17 (val, wt) pairs once, no atomics (z=16 is empty pre-blur)
    float2* dst = (float2*)grid + (size_t)idx * GZ;
    #pragma unroll
    for (int z = 0; z < 16; ++z) {
        float2 o; o.x = lval[z * 256 + tid]; o.y = lwt[z * 256 + tid];
        dst[z] = o;
    }
    float2 zero; zero.x = 0.f; zero.y = 0.f;
    dst[16] = zero;
}

// ---- blur along y, one thread per z-column ----
__global__ __launch_bounds__(256) void blur_y_col(
    const float2* __restrict__ in, float2* __restrict__ out,
    const float* __restrict__ kf, int nImg)
{
    int col = blockIdx.x * blockDim.x + threadIdx.x;
    int total = nImg * GH * GW;
    if (col >= total) return;
    int b   = col / (GH * GW);
    int rem = col - b * (GH * GW);
    int y   = rem / GW;

    float kk[5] = {kf[0], kf[1], kf[2], kf[3], kf[4]};

    float2 acc[GZ];
    #pragma unroll
    for (int z = 0; z < GZ; ++z) { acc[z].x = 0.f; acc[z].y = 0.f; }

    #pragma unroll
    for (int t = 0; t < 5; ++t) {
        int yy = y + t - 2;
        if (yy >= 0 && yy < GH) {
            const float2* src = in + (size_t)(col + (t - 2) * GW) * GZ;
            float k = kk[t];
            #pragma unroll
            for (int z = 0; z < GZ; ++z) {
                float2 g = src[z];
                acc[z].x += k * g.x;
                acc[z].y += k * g.y;
            }
        }
    }
    float2* dst = out + (size_t)col * GZ;
    #pragma unroll
    for (int z = 0; z < GZ; ++z) dst[z] = acc[z];
}

// ---- fused blur along x then z, one thread per z-column ----
__global__ __launch_bounds__(256) void blur_xz_col(
    const float2* __restrict__ in, float2* __restrict__ out,
    const float* __restrict__ kfs, const float* __restrict__ kfr, int nImg)
{
    int col = blockIdx.x * blockDim.x + threadIdx.x;
    int total = nImg * GH * GW;
    if (col >= total) return;
    int b   = col / (GH * GW);
    int rem = col - b * (GH * GW);
    int x   = rem % GW;

    float ks[5] = {kfs[0], kfs[1], kfs[2], kfs[3], kfs[4]};
    float kr[5] = {kfr[0], kfr[1], kfr[2], kfr[3], kfr[4]};

    float2 tmp[GZ];
    #pragma unroll
    for (int z = 0; z < GZ; ++z) { tmp[z].x = 0.f; tmp[z].y = 0.f; }

    #pragma unroll
    for (int t = 0; t < 5; ++t) {
        int xx = x + t - 2;
        if (xx >= 0 && xx < GW) {
            const float2* src = in + (size_t)(col + (t - 2)) * GZ;
            float k = ks[t];
            #pragma unroll
            for (int z = 0; z < GZ; ++z) {
                float2 g = src[z];
                tmp[z].x += k * g.x;
                tmp[z].y += k * g.y;
            }
        }
    }
    float2* dst = out + (size_t)col * GZ;
    #pragma unroll
    for (int z = 0; z < GZ; ++z) {
        float av = 0.f, aw = 0.f;
        #pragma unroll
        for (int t = 0; t < 5; ++t) {
            int zz = z + t - 2;
            if (zz >= 0 && zz < GZ) {
                av += kr[t] * tmp[zz].x;
                aw += kr[t] * tmp[zz].y;
            }
        }
        float2 o; o.x = av; o.y = aw;
        dst[z] = o;
    }
}

__global__ __launch_bounds__(256) void slice_kernel(
    const float* __restrict__ img, const float2* __restrict__ grid,
    float* __restrict__ out, int nImg, int imgBase)
{
    int total = nImg * HDIM * WDIM;
    for (int idx = blockIdx.x * blockDim.x + threadIdx.x; idx < total;
         idx += gridDim.x * blockDim.x) {
        int b   = idx / (HDIM * WDIM);
        int rem = idx - b * (HDIM * WDIM);
        int y   = rem / WDIM;
        int x   = rem - y * WDIM;
        float v = img[(size_t)(imgBase + b) * (HDIM * WDIM) + rem];

        float fy = (float)y * 0.125f;
        float fx = (float)x * 0.125f;
        float fz = fminf(fmaxf(v * 15.0f, 0.0f), 15.0f);
        int y0 = (int)floorf(fy);
        int x0 = (int)floorf(fx);
        int z0 = (int)floorf(fz);
        int y1 = min(y0 + 1, GH - 1);
        int x1 = min(x0 + 1, GW - 1);
        int z1 = min(z0 + 1, GZ - 1);
        float ty = fy - (float)y0;
        float tx = fx - (float)x0;
        float tz = fz - (float)z0;

        const float2* gb = grid + (size_t)b * CELLS;
        float ov = 0.f, ow = 0.f;
        int   yis[2] = {y0, y1};     float wys[2] = {1.f - ty, ty};
        int   xis[2] = {x0, x1};     float wxs[2] = {1.f - tx, tx};
        int   zis[2] = {z0, z1};     float wzs[2] = {1.f - tz, tz};
        #pragma unroll
        for (int a = 0; a < 2; ++a) {
            #pragma unroll
            for (int c = 0; c < 2; ++c) {
                int base = (yis[a] * GW + xis[c]) * GZ;
                float wyx = wys[a] * wxs[c];
                #pragma unroll
                for (int d = 0; d < 2; ++d) {
                    float w = wyx * wzs[d];
                    float2 g = gb[base + zis[d]];
                    ov += w * g.x;
                    ow += w * g.y;
                }
            }
        }
        out[(size_t)(imgBase + b) * (HDIM * WDIM) + rem] = ov / (ow + EPSV);
    }
}

extern "C" void kernel_launch(void* const* d_in, const int* in_sizes, int n_in,
                              void* d_out, int out_size, void* d_ws, size_t ws_size,
                              hipStream_t stream)
{
    const float* img = (const float*)d_in[0];
    const float* fs  = (const float*)d_in[2];
    const float* fr  = (const float*)d_in[3];
    float* out = (float*)d_out;

    int nImgTotal = in_sizes[0] / (HDIM * WDIM);   // 12
    size_t perImgBytes = (size_t)CELLS * 2 * sizeof(float);

    int maxChunk = (int)(ws_size / (2 * perImgBytes));
    if (maxChunk < 1) return;
    if (maxChunk > nImgTotal) maxChunk = nImgTotal;

    for (int base = 0; base < nImgTotal; base += maxChunk) {
        int c = nImgTotal - base;
        if (c > maxChunk) c = maxChunk;

        float* A = (float*)d_ws;
        float* B = A + (size_t)c * CELLS * 2;

        int nCols = c * GH * GW;
        int colBlocks = (nCols + 255) / 256;

        splat_gather_kernel<<<colBlocks, 256, 0, stream>>>(img, A, c, base);
        blur_y_col <<<colBlocks, 256, 0, stream>>>((const float2*)A, (float2*)B, fs, c);
        blur_xz_col<<<colBlocks, 256, 0, stream>>>((const float2*)B, (float2*)A, fs, fr, c);

        int nPix = c * HDIM * WDIM;
        int pixBlocks = min((nPix + 255) / 256, 4096);
        slice_kernel<<<pixBlocks, 256, 0, stream>>>(img, (const float2*)A, out, c, base);
    }
}

// Round 4
// 135.768 us; speedup vs baseline: 5.6800x; 1.1599x over previous
//
#include <hip/hip_runtime.h>

#define S_SIGMA 8
#define NBINS   16
#define HDIM    1024
#define WDIM    1024
#define GH      129   // (1024-1)/8 + 2
#define GW      129
#define GZ      17    // NBINS + 1
#define CELLS   (GH*GW*GZ)   // 282897 cells per image
#define EPSV    1e-8f

// ---- gather splat: one thread per spatial cell (b,gy,gx), no atomics ----
// Banker's rounding footprint: even g -> [8g-4, 8g+4], odd g -> [8g-3, 8g+3].
__global__ __launch_bounds__(256) void splat_gather_kernel(
    const float* __restrict__ img, float* __restrict__ grid, int nImg, int imgBase)
{
    __shared__ float lval[16 * 256];   // [gz][tid] -> bank = tid%32, conflict-free
    __shared__ float lwt [16 * 256];

    int tid = threadIdx.x;
    int idx = blockIdx.x * blockDim.x + tid;
    int total = nImg * GH * GW;
    if (idx >= total) return;

    int b   = idx / (GH * GW);
    int rem = idx - b * (GH * GW);
    int gy  = rem / GW;
    int gx  = rem - gy * GW;

    #pragma unroll
    for (int z = 0; z < 16; ++z) { lval[z * 256 + tid] = 0.f; lwt[z * 256 + tid] = 0.f; }

    int ylo = max(0, 8 * gy - 4 + (gy & 1));
    int yhi = min(HDIM - 1, 8 * gy + 4 - (gy & 1));
    int xlo = max(0, 8 * gx - 4 + (gx & 1));
    int xhi = min(WDIM - 1, 8 * gx + 4 - (gx & 1));

    const float* ib = img + (size_t)(imgBase + b) * (HDIM * WDIM);
    for (int y = ylo; y <= yhi; ++y) {
        const float* row = ib + (size_t)y * WDIM;
        for (int x = xlo; x <= xhi; ++x) {
            float v = row[x];
            int gz = (int)rintf(v * 15.0f);      // banker's rounding = jnp.round
            gz = min(max(gz, 0), 15);
            lval[gz * 256 + tid] += v;
            lwt [gz * 256 + tid] += 1.0f;
        }
    }

    float2* dst = (float2*)grid + (size_t)idx * GZ;
    #pragma unroll
    for (int z = 0; z < 16; ++z) {
        float2 o; o.x = lval[z * 256 + tid]; o.y = lwt[z * 256 + tid];
        dst[z] = o;
    }
    float2 zero; zero.x = 0.f; zero.y = 0.f;
    dst[16] = zero;
}

// ---- fused y+x+z blur, LDS tiled: 12x12 output cells per block ----
#define TO 12              // output tile (cells)
#define TI 16              // input tile with +-2 halo
#define NIN  (TI*TI*GZ)    // 4352
#define NTMP (TO*TI*GZ)    // 3264
#define NOUT (TO*TO*GZ)    // 2448

__global__ __launch_bounds__(256) void blur_fused_kernel(
    const float2* __restrict__ in, float2* __restrict__ out,
    const float* __restrict__ kfs, const float* __restrict__ kfr)
{
    __shared__ float2 sbin[NIN];    // input tile; reused as x-blur output
    __shared__ float2 stmp[NTMP];   // y-blurred

    int tid = threadIdx.x;
    int tx0 = blockIdx.x * TO;
    int ty0 = blockIdx.y * TO;
    int b   = blockIdx.z;

    float ks[5] = {kfs[0], kfs[1], kfs[2], kfs[3], kfs[4]};
    float kr[5] = {kfr[0], kfr[1], kfr[2], kfr[3], kfr[4]};

    // ---- load tile (zero pad outside grid) ----
    const float2* gb = in + (size_t)b * CELLS;
    for (int li = tid; li < NIN; li += 256) {
        int iy = li / (TI * GZ);
        int r  = li - iy * (TI * GZ);
        int ix = r / GZ;
        int z  = r - ix * GZ;
        int gy = ty0 - 2 + iy;
        int gx = tx0 - 2 + ix;
        float2 v; v.x = 0.f; v.y = 0.f;
        if (gy >= 0 && gy < GH && gx >= 0 && gx < GW)
            v = gb[((size_t)gy * GW + gx) * GZ + z];
        sbin[li] = v;
    }
    __syncthreads();

    // ---- y blur: stmp[oy][ix][z] ----
    for (int o = tid; o < NTMP; o += 256) {
        int oy = o / (TI * GZ);
        int r  = o - oy * (TI * GZ);
        float2 a; a.x = 0.f; a.y = 0.f;
        #pragma unroll
        for (int t = 0; t < 5; ++t) {
            float2 g = sbin[(oy + t) * (TI * GZ) + r];
            a.x += ks[t] * g.x;
            a.y += ks[t] * g.y;
        }
        stmp[o] = a;
    }
    __syncthreads();

    // ---- x blur -> reuse sbin[0..NOUT) as xb[oy][ox][z] ----
    for (int o = tid; o < NOUT; o += 256) {
        int oy = o / (TO * GZ);
        int r  = o - oy * (TO * GZ);
        int ox = r / GZ;
        int z  = r - ox * GZ;
        float2 a; a.x = 0.f; a.y = 0.f;
        #pragma unroll
        for (int t = 0; t < 5; ++t) {
            float2 g = stmp[(oy * TI + ox + t) * GZ + z];
            a.x += ks[t] * g.x;
            a.y += ks[t] * g.y;
        }
        sbin[o] = a;
    }
    __syncthreads();

    // ---- z blur (zero pad) + store ----
    float2* ob = out + (size_t)b * CELLS;
    for (int o = tid; o < NOUT; o += 256) {
        int oy = o / (TO * GZ);
        int r  = o - oy * (TO * GZ);
        int ox = r / GZ;
        int z  = r - ox * GZ;
        int gy = ty0 + oy;
        int gx = tx0 + ox;
        if (gy < GH && gx < GW) {
            int base = o - z;   // (oy*TO+ox)*GZ
            float2 a; a.x = 0.f; a.y = 0.f;
            #pragma unroll
            for (int t = 0; t < 5; ++t) {
                int zz = z + t - 2;
                if (zz >= 0 && zz < GZ) {
                    float2 g = sbin[base + zz];
                    a.x += kr[t] * g.x;
                    a.y += kr[t] * g.y;
                }
            }
            ob[((size_t)gy * GW + gx) * GZ + z] = a;
        }
    }
}

// ---- slice: 4 pixels per thread, float4 in/out ----
__global__ __launch_bounds__(256) void slice4_kernel(
    const float* __restrict__ img, const float2* __restrict__ grid,
    float* __restrict__ out, int nImg, int imgBase)
{
    int idx = blockIdx.x * blockDim.x + threadIdx.x;
    int total = nImg * (HDIM * WDIM / 4);
    if (idx >= total) return;

    int b   = idx / (HDIM * WDIM / 4);
    int rem = idx - b * (HDIM * WDIM / 4);
    int y   = rem >> 8;        // / (WDIM/4)
    int xg  = rem & 255;
    int x   = xg << 2;

    size_t pixBase = (size_t)(imgBase + b) * (HDIM * WDIM) + (size_t)y * WDIM + x;
    float4 v4 = *(const float4*)(img + pixBase);

    int y0 = y >> 3;
    float ty = (float)(y - (y0 << 3)) * 0.125f;
    int x0 = x >> 3;
    float txb = (float)(x - (x0 << 3)) * 0.125f;

    const float2* gb  = grid + (size_t)b * CELLS;
    const float2* p00 = gb + ((size_t)y0 * GW + x0) * GZ;        // (y0,x0)
    const float2* p10 = gb + ((size_t)(y0 + 1) * GW + x0) * GZ;  // (y1,x0); y0<=127 so y1<=128 ok
    float wy0 = 1.f - ty, wy1 = ty;

    float vv[4] = {v4.x, v4.y, v4.z, v4.w};
    float rr[4];
    #pragma unroll
    for (int j = 0; j < 4; ++j) {
        float v  = vv[j];
        float fz = fminf(fmaxf(v * 15.0f, 0.0f), 15.0f);
        float zf = floorf(fz);
        int   z0 = (int)zf;
        float tz = fz - zf;
        float tx = txb + (float)j * 0.125f;     // same 8-block for all 4 px
        float wx0 = 1.f - tx, wx1 = tx;
        float wz0 = 1.f - tz, wz1 = tz;

        float2 g000 = p00[z0],      g001 = p00[z0 + 1];
        float2 g010 = p00[GZ + z0], g011 = p00[GZ + z0 + 1];
        float2 g100 = p10[z0],      g101 = p10[z0 + 1];
        float2 g110 = p10[GZ + z0], g111 = p10[GZ + z0 + 1];

        float ov = 0.f, ow = 0.f, w;
        // reference nesting order: y outer, x mid, z inner
        w = wy0 * wx0 * wz0; ov += w * g000.x; ow += w * g000.y;
        w = wy0 * wx0 * wz1; ov += w * g001.x; ow += w * g001.y;
        w = wy0 * wx1 * wz0; ov += w * g010.x; ow += w * g010.y;
        w = wy0 * wx1 * wz1; ov += w * g011.x; ow += w * g011.y;
        w = wy1 * wx0 * wz0; ov += w * g100.x; ow += w * g100.y;
        w = wy1 * wx0 * wz1; ov += w * g101.x; ow += w * g101.y;
        w = wy1 * wx1 * wz0; ov += w * g110.x; ow += w * g110.y;
        w = wy1 * wx1 * wz1; ov += w * g111.x; ow += w * g111.y;
        rr[j] = ov / (ow + EPSV);
    }
    float4 r4; r4.x = rr[0]; r4.y = rr[1]; r4.z = rr[2]; r4.w = rr[3];
    *(float4*)(out + pixBase) = r4;
}

extern "C" void kernel_launch(void* const* d_in, const int* in_sizes, int n_in,
                              void* d_out, int out_size, void* d_ws, size_t ws_size,
                              hipStream_t stream)
{
    const float* img = (const float*)d_in[0];
    const float* fs  = (const float*)d_in[2];
    const float* fr  = (const float*)d_in[3];
    float* out = (float*)d_out;

    int nImgTotal = in_sizes[0] / (HDIM * WDIM);   // 12
    size_t perImgBytes = (size_t)CELLS * 2 * sizeof(float);

    int maxChunk = (int)(ws_size / (2 * perImgBytes));
    if (maxChunk < 1) return;
    if (maxChunk > nImgTotal) maxChunk = nImgTotal;

    const int tilesPerDim = (GH + TO - 1) / TO;    // 11

    for (int base = 0; base < nImgTotal; base += maxChunk) {
        int c = nImgTotal - base;
        if (c > maxChunk) c = maxChunk;

        float* A = (float*)d_ws;
        float* B = A + (size_t)c * CELLS * 2;

        int nCols = c * GH * GW;
        int colBlocks = (nCols + 255) / 256;
        splat_gather_kernel<<<colBlocks, 256, 0, stream>>>(img, A, c, base);

        dim3 bgrid(tilesPerDim, tilesPerDim, c);
        blur_fused_kernel<<<bgrid, 256, 0, stream>>>((const float2*)A, (float2*)B, fs, fr);

        int nQuads = c * (HDIM * WDIM / 4);
        int qBlocks = (nQuads + 255) / 256;
        slice4_kernel<<<qBlocks, 256, 0, stream>>>(img, (const float2*)B, out, c, base);
    }
}

// Round 5
// 115.733 us; speedup vs baseline: 6.6633x; 1.1731x over previous
//
#include <hip/hip_runtime.h>

#define S_SIGMA 8
#define NBINS   16
#define HDIM    1024
#define WDIM    1024
#define GH      129   // (1024-1)/8 + 2
#define GW      129
#define GZ      17    // NBINS + 1
#define CELLS   (GH*GW*GZ)   // 282897 cells per image
#define ROWSZ   (GW*GZ)      // 2193 float2 per grid row
#define EPSV    1e-8f

// ---- gather splat: one thread per spatial cell (b,gy,gx), no atomics ----
// Banker's rounding footprint: even g -> [8g-4, 8g+4], odd g -> [8g-3, 8g+3].
__global__ __launch_bounds__(256) void splat_gather_kernel(
    const float* __restrict__ img, float* __restrict__ grid, int nImg, int imgBase)
{
    __shared__ float lval[16 * 256];   // [gz][tid] -> bank = tid%32, conflict-free
    __shared__ float lwt [16 * 256];

    int tid = threadIdx.x;
    int idx = blockIdx.x * blockDim.x + tid;
    int total = nImg * GH * GW;
    if (idx >= total) return;

    int b   = idx / (GH * GW);
    int rem = idx - b * (GH * GW);
    int gy  = rem / GW;
    int gx  = rem - gy * GW;

    #pragma unroll
    for (int z = 0; z < 16; ++z) { lval[z * 256 + tid] = 0.f; lwt[z * 256 + tid] = 0.f; }

    const float* ib = img + (size_t)(imgBase + b) * (HDIM * WDIM);

    bool interior = (gx >= 1) & (gx <= 127) & (gy >= 1) & (gy <= 127);
    if (interior) {
        int py = gy & 1, px = gx & 1;
        int ylo = 8 * gy - 4 + py;
        int nr  = 9 - 2 * py;
        int ax  = 8 * gx - 4;           // 4-aligned -> float4 loads are 16B aligned
        #pragma unroll
        for (int r = 0; r < 9; ++r) {
            if (r < nr) {
                const float* rp = ib + (size_t)(ylo + r) * WDIM + ax;
                float4 A = *(const float4*)rp;
                float4 B = *(const float4*)(rp + 4);
                float  cv = rp[8];
                float e7[7] = {A.y, A.z, A.w, B.x, B.y, B.z, B.w};
                #pragma unroll
                for (int j = 0; j < 7; ++j) {
                    float v = e7[j];
                    int gz = min(max((int)rintf(v * 15.0f), 0), 15);
                    lval[gz * 256 + tid] += v;
                    lwt [gz * 256 + tid] += 1.0f;
                }
                if (!px) {   // even gx also owns A.x (x=8gx-4) and cv (x=8gx+4)
                    int gz = min(max((int)rintf(A.x * 15.0f), 0), 15);
                    lval[gz * 256 + tid] += A.x;
                    lwt [gz * 256 + tid] += 1.0f;
                    gz = min(max((int)rintf(cv * 15.0f), 0), 15);
                    lval[gz * 256 + tid] += cv;
                    lwt [gz * 256 + tid] += 1.0f;
                }
            }
        }
    } else {
        int ylo = max(0, 8 * gy - 4 + (gy & 1));
        int yhi = min(HDIM - 1, 8 * gy + 4 - (gy & 1));
        int xlo = max(0, 8 * gx - 4 + (gx & 1));
        int xhi = min(WDIM - 1, 8 * gx + 4 - (gx & 1));
        for (int y = ylo; y <= yhi; ++y) {
            const float* row = ib + (size_t)y * WDIM;
            for (int x = xlo; x <= xhi; ++x) {
                float v = row[x];
                int gz = min(max((int)rintf(v * 15.0f), 0), 15);
                lval[gz * 256 + tid] += v;
                lwt [gz * 256 + tid] += 1.0f;
            }
        }
    }

    float2* dst = (float2*)grid + (size_t)idx * GZ;
    #pragma unroll
    for (int z = 0; z < 16; ++z) {
        float2 o; o.x = lval[z * 256 + tid]; o.y = lwt[z * 256 + tid];
        dst[z] = o;
    }
    float2 zero; zero.x = 0.f; zero.y = 0.f;
    dst[16] = zero;
}

// ---- fused y+x+z blur, LDS tiled: 12x12 output cells per block ----
#define TO 12              // output tile (cells)
#define TI 16              // input tile with +-2 halo
#define NIN  (TI*TI*GZ)    // 4352
#define NTMP (TO*TI*GZ)    // 3264
#define NOUT (TO*TO*GZ)    // 2448

__global__ __launch_bounds__(256) void blur_fused_kernel(
    const float2* __restrict__ in, float2* __restrict__ out,
    const float* __restrict__ kfs, const float* __restrict__ kfr)
{
    __shared__ float2 sbin[NIN];    // input tile; reused as x-blur output
    __shared__ float2 stmp[NTMP];   // y-blurred

    int tid = threadIdx.x;
    int tx0 = blockIdx.x * TO;
    int ty0 = blockIdx.y * TO;
    int b   = blockIdx.z;

    float ks[5] = {kfs[0], kfs[1], kfs[2], kfs[3], kfs[4]};
    float kr[5] = {kfr[0], kfr[1], kfr[2], kfr[3], kfr[4]};

    const float2* gb = in + (size_t)b * CELLS;
    for (int li = tid; li < NIN; li += 256) {
        int iy = li / (TI * GZ);
        int r  = li - iy * (TI * GZ);
        int ix = r / GZ;
        int z  = r - ix * GZ;
        int gy = ty0 - 2 + iy;
        int gx = tx0 - 2 + ix;
        float2 v; v.x = 0.f; v.y = 0.f;
        if (gy >= 0 && gy < GH && gx >= 0 && gx < GW)
            v = gb[((size_t)gy * GW + gx) * GZ + z];
        sbin[li] = v;
    }
    __syncthreads();

    for (int o = tid; o < NTMP; o += 256) {
        int oy = o / (TI * GZ);
        int r  = o - oy * (TI * GZ);
        float2 a; a.x = 0.f; a.y = 0.f;
        #pragma unroll
        for (int t = 0; t < 5; ++t) {
            float2 g = sbin[(oy + t) * (TI * GZ) + r];
            a.x += ks[t] * g.x;
            a.y += ks[t] * g.y;
        }
        stmp[o] = a;
    }
    __syncthreads();

    for (int o = tid; o < NOUT; o += 256) {
        int oy = o / (TO * GZ);
        int r  = o - oy * (TO * GZ);
        int ox = r / GZ;
        int z  = r - ox * GZ;
        float2 a; a.x = 0.f; a.y = 0.f;
        #pragma unroll
        for (int t = 0; t < 5; ++t) {
            float2 g = stmp[(oy * TI + ox + t) * GZ + z];
            a.x += ks[t] * g.x;
            a.y += ks[t] * g.y;
        }
        sbin[o] = a;
    }
    __syncthreads();

    float2* ob = out + (size_t)b * CELLS;
    for (int o = tid; o < NOUT; o += 256) {
        int oy = o / (TO * GZ);
        int r  = o - oy * (TO * GZ);
        int ox = r / GZ;
        int z  = r - ox * GZ;
        int gy = ty0 + oy;
        int gx = tx0 + ox;
        if (gy < GH && gx < GW) {
            int base = o - z;
            float2 a; a.x = 0.f; a.y = 0.f;
            #pragma unroll
            for (int t = 0; t < 5; ++t) {
                int zz = z + t - 2;
                if (zz >= 0 && zz < GZ) {
                    float2 g = sbin[base + zz];
                    a.x += kr[t] * g.x;
                    a.y += kr[t] * g.y;
                }
            }
            ob[((size_t)gy * GW + gx) * GZ + z] = a;
        }
    }
}

// ---- slice: block = (8-pixel-row group, image); grid rows staged in LDS ----
__global__ __launch_bounds__(256) void slice_rows_kernel(
    const float* __restrict__ img, const float2* __restrict__ grid,
    float* __restrict__ out, int imgBase)
{
    __shared__ float2 srow[2 * ROWSZ];   // rows k, k+1 : 4386 float2 = 35 KB

    int tid = threadIdx.x;
    int k   = blockIdx.x;    // 0..127
    int b   = blockIdx.y;

    // stage two contiguous grid rows (coalesced)
    const float2* gsrc = grid + (size_t)b * CELLS + (size_t)k * ROWSZ;
    for (int i = tid; i < 2 * ROWSZ; i += 256) srow[i] = gsrc[i];
    __syncthreads();

    int x  = tid << 2;           // 4 px per thread per row
    int x0 = tid >> 1;           // x>>3
    float txb = (float)(x & 7) * 0.125f;
    const float2* p00 = srow + x0 * GZ;
    const float2* p10 = p00 + ROWSZ;

    size_t rowBase = (size_t)(imgBase + b) * (HDIM * WDIM) + (size_t)(k << 3) * WDIM + x;

    #pragma unroll
    for (int r = 0; r < 8; ++r) {
        size_t pixBase = rowBase + (size_t)r * WDIM;
        float4 v4 = *(const float4*)(img + pixBase);
        float ty = (float)r * 0.125f;
        float wy0 = 1.f - ty, wy1 = ty;

        float vv[4] = {v4.x, v4.y, v4.z, v4.w};
        float rr[4];
        #pragma unroll
        for (int j = 0; j < 4; ++j) {
            float v  = vv[j];
            float fz = fminf(fmaxf(v * 15.0f, 0.0f), 15.0f);
            float zf = floorf(fz);
            int   z0 = (int)zf;
            float tz = fz - zf;
            float tx = txb + (float)j * 0.125f;
            float wx0 = 1.f - tx, wx1 = tx;
            float wz0 = 1.f - tz, wz1 = tz;

            float2 g000 = p00[z0],      g001 = p00[z0 + 1];
            float2 g010 = p00[GZ + z0], g011 = p00[GZ + z0 + 1];
            float2 g100 = p10[z0],      g101 = p10[z0 + 1];
            float2 g110 = p10[GZ + z0], g111 = p10[GZ + z0 + 1];

            float ov = 0.f, ow = 0.f, w;
            w = wy0 * wx0 * wz0; ov += w * g000.x; ow += w * g000.y;
            w = wy0 * wx0 * wz1; ov += w * g001.x; ow += w * g001.y;
            w = wy0 * wx1 * wz0; ov += w * g010.x; ow += w * g010.y;
            w = wy0 * wx1 * wz1; ov += w * g011.x; ow += w * g011.y;
            w = wy1 * wx0 * wz0; ov += w * g100.x; ow += w * g100.y;
            w = wy1 * wx0 * wz1; ov += w * g101.x; ow += w * g101.y;
            w = wy1 * wx1 * wz0; ov += w * g110.x; ow += w * g110.y;
            w = wy1 * wx1 * wz1; ov += w * g111.x; ow += w * g111.y;
            rr[j] = ov / (ow + EPSV);
        }
        float4 r4; r4.x = rr[0]; r4.y = rr[1]; r4.z = rr[2]; r4.w = rr[3];
        *(float4*)(out + pixBase) = r4;
    }
}

extern "C" void kernel_launch(void* const* d_in, const int* in_sizes, int n_in,
                              void* d_out, int out_size, void* d_ws, size_t ws_size,
                              hipStream_t stream)
{
    const float* img = (const float*)d_in[0];
    const float* fs  = (const float*)d_in[2];
    const float* fr  = (const float*)d_in[3];
    float* out = (float*)d_out;

    int nImgTotal = in_sizes[0] / (HDIM * WDIM);   // 12
    size_t perImgBytes = (size_t)CELLS * 2 * sizeof(float);

    int maxChunk = (int)(ws_size / (2 * perImgBytes));
    if (maxChunk < 1) return;
    if (maxChunk > nImgTotal) maxChunk = nImgTotal;

    const int tilesPerDim = (GH + TO - 1) / TO;    // 11

    for (int base = 0; base < nImgTotal; base += maxChunk) {
        int c = nImgTotal - base;
        if (c > maxChunk) c = maxChunk;

        float* A = (float*)d_ws;
        float* B = A + (size_t)c * CELLS * 2;

        int nCols = c * GH * GW;
        int colBlocks = (nCols + 255) / 256;
        splat_gather_kernel<<<colBlocks, 256, 0, stream>>>(img, A, c, base);

        dim3 bgrid(tilesPerDim, tilesPerDim, c);
        blur_fused_kernel<<<bgrid, 256, 0, stream>>>((const float2*)A, (float2*)B, fs, fr);

        dim3 sgrid(HDIM / 8, c);
        slice_rows_kernel<<<sgrid, 256, 0, stream>>>(img, (const float2*)B, out, base);
    }
}

// Round 6
// 112.129 us; speedup vs baseline: 6.8775x; 1.0321x over previous
//
#include <hip/hip_runtime.h>

#define S_SIGMA 8
#define NBINS   16
#define HDIM    1024
#define WDIM    1024
#define GH      129   // (1024-1)/8 + 2
#define GW      129
#define GZ      17    // NBINS + 1
#define CELLS   (GH*GW*GZ)   // 282897 cells per image
#define ROWSZ   (GW*GZ)      // 2193 float2 per grid row
#define EPSV    1e-8f

// ---- gather splat: one thread per spatial cell, 64-thread blocks ----
// Banker's rounding footprint: even g -> [8g-4, 8g+4], odd g -> [8g-3, 8g+3].
__global__ __launch_bounds__(64) void splat_gather_kernel(
    const float* __restrict__ img, float* __restrict__ grid, int nImg, int imgBase)
{
    __shared__ float lval[16 * 64];   // [gz][tid] -> bank = tid%32, 2-way free
    __shared__ float lwt [16 * 64];

    int tid = threadIdx.x;
    int idx = blockIdx.x * 64 + tid;
    int total = nImg * GH * GW;
    if (idx >= total) return;

    int b   = idx / (GH * GW);
    int rem = idx - b * (GH * GW);
    int gy  = rem / GW;
    int gx  = rem - gy * GW;

    #pragma unroll
    for (int z = 0; z < 16; ++z) { lval[z * 64 + tid] = 0.f; lwt[z * 64 + tid] = 0.f; }

    const float* ib = img + (size_t)(imgBase + b) * (HDIM * WDIM);

    bool interior = (gx >= 1) & (gx <= 127) & (gy >= 1) & (gy <= 127);
    if (interior) {
        int py = gy & 1, px = gx & 1;
        int ylo = 8 * gy - 4 + py;
        int nr  = 9 - 2 * py;
        int ax  = 8 * gx - 4;           // 4-aligned -> 16B-aligned float4 loads
        #pragma unroll
        for (int r = 0; r < 9; ++r) {
            if (r < nr) {
                const float* rp = ib + (size_t)(ylo + r) * WDIM + ax;
                float4 A = *(const float4*)rp;
                float4 B = *(const float4*)(rp + 4);
                float  cv = rp[8];
                float e7[7] = {A.y, A.z, A.w, B.x, B.y, B.z, B.w};
                #pragma unroll
                for (int j = 0; j < 7; ++j) {
                    float v = e7[j];
                    int gz = min(max((int)rintf(v * 15.0f), 0), 15);
                    lval[gz * 64 + tid] += v;
                    lwt [gz * 64 + tid] += 1.0f;
                }
                if (!px) {   // even gx also owns A.x and cv
                    int gz = min(max((int)rintf(A.x * 15.0f), 0), 15);
                    lval[gz * 64 + tid] += A.x;
                    lwt [gz * 64 + tid] += 1.0f;
                    gz = min(max((int)rintf(cv * 15.0f), 0), 15);
                    lval[gz * 64 + tid] += cv;
                    lwt [gz * 64 + tid] += 1.0f;
                }
            }
        }
    } else {
        int ylo = max(0, 8 * gy - 4 + (gy & 1));
        int yhi = min(HDIM - 1, 8 * gy + 4 - (gy & 1));
        int xlo = max(0, 8 * gx - 4 + (gx & 1));
        int xhi = min(WDIM - 1, 8 * gx + 4 - (gx & 1));
        for (int y = ylo; y <= yhi; ++y) {
            const float* row = ib + (size_t)y * WDIM;
            for (int x = xlo; x <= xhi; ++x) {
                float v = row[x];
                int gz = min(max((int)rintf(v * 15.0f), 0), 15);
                lval[gz * 64 + tid] += v;
                lwt [gz * 64 + tid] += 1.0f;
            }
        }
    }

    float2* dst = (float2*)grid + (size_t)idx * GZ;
    #pragma unroll
    for (int z = 0; z < 16; ++z) {
        float2 o; o.x = lval[z * 64 + tid]; o.y = lwt[z * 64 + tid];
        dst[z] = o;
    }
    float2 zero; zero.x = 0.f; zero.y = 0.f;
    dst[16] = zero;
}

// ---- fused y+x+z blur, LDS tiled: 12x12 output cells per block ----
#define TO 12
#define TI 16
#define NIN  (TI*TI*GZ)    // 4352
#define NTMP (TO*TI*GZ)    // 3264
#define NOUT (TO*TO*GZ)    // 2448

__global__ __launch_bounds__(256) void blur_fused_kernel(
    const float2* __restrict__ in, float2* __restrict__ out,
    const float* __restrict__ kfs, const float* __restrict__ kfr)
{
    __shared__ float2 sbin[NIN];
    __shared__ float2 stmp[NTMP];

    int tid = threadIdx.x;
    int tx0 = blockIdx.x * TO;
    int ty0 = blockIdx.y * TO;
    int b   = blockIdx.z;

    float ks[5] = {kfs[0], kfs[1], kfs[2], kfs[3], kfs[4]};
    float kr[5] = {kfr[0], kfr[1], kfr[2], kfr[3], kfr[4]};

    const float2* gb = in + (size_t)b * CELLS;
    for (int li = tid; li < NIN; li += 256) {
        int iy = li / (TI * GZ);
        int r  = li - iy * (TI * GZ);
        int ix = r / GZ;
        int z  = r - ix * GZ;
        int gy = ty0 - 2 + iy;
        int gx = tx0 - 2 + ix;
        float2 v; v.x = 0.f; v.y = 0.f;
        if (gy >= 0 && gy < GH && gx >= 0 && gx < GW)
            v = gb[((size_t)gy * GW + gx) * GZ + z];
        sbin[li] = v;
    }
    __syncthreads();

    for (int o = tid; o < NTMP; o += 256) {
        int oy = o / (TI * GZ);
        int r  = o - oy * (TI * GZ);
        float2 a; a.x = 0.f; a.y = 0.f;
        #pragma unroll
        for (int t = 0; t < 5; ++t) {
            float2 g = sbin[(oy + t) * (TI * GZ) + r];
            a.x += ks[t] * g.x;
            a.y += ks[t] * g.y;
        }
        stmp[o] = a;
    }
    __syncthreads();

    for (int o = tid; o < NOUT; o += 256) {
        int oy = o / (TO * GZ);
        int r  = o - oy * (TO * GZ);
        int ox = r / GZ;
        int z  = r - ox * GZ;
        float2 a; a.x = 0.f; a.y = 0.f;
        #pragma unroll
        for (int t = 0; t < 5; ++t) {
            float2 g = stmp[(oy * TI + ox + t) * GZ + z];
            a.x += ks[t] * g.x;
            a.y += ks[t] * g.y;
        }
        sbin[o] = a;
    }
    __syncthreads();

    float2* ob = out + (size_t)b * CELLS;
    for (int o = tid; o < NOUT; o += 256) {
        int oy = o / (TO * GZ);
        int r  = o - oy * (TO * GZ);
        int ox = r / GZ;
        int z  = r - ox * GZ;
        int gy = ty0 + oy;
        int gx = tx0 + ox;
        if (gy < GH && gx < GW) {
            int base = o - z;
            float2 a; a.x = 0.f; a.y = 0.f;
            #pragma unroll
            for (int t = 0; t < 5; ++t) {
                int zz = z + t - 2;
                if (zz >= 0 && zz < GZ) {
                    float2 g = sbin[base + zz];
                    a.x += kr[t] * g.x;
                    a.y += kr[t] * g.y;
                }
            }
            ob[((size_t)gy * GW + gx) * GZ + z] = a;
        }
    }
}

// ---- slice: transposed conflict-free LDS [z][r][x0pad], bank = x0 % 32 ----
#define PADX  160                   // multiple of 32; x0 needs 0..128
#define ZSTR  (2*PADX)              // 320 floats per z-plane
#define AHALF (GZ*ZSTR)             // 5440 floats per array (val | wt)

__global__ __launch_bounds__(256) void slice_rows_kernel(
    const float* __restrict__ img, const float2* __restrict__ grid,
    float* __restrict__ out, int imgBase)
{
    __shared__ float sls[2 * AHALF];   // [val | wt], 43520 B

    int tid = threadIdx.x;
    int k   = blockIdx.x;    // 0..127 (8-pixel-row group)
    int b   = blockIdx.y;

    // stage two contiguous grid rows, transposing to [z][r][x0]
    const float2* gsrc = grid + (size_t)b * CELLS + (size_t)k * ROWSZ;
    for (int i = tid; i < 2 * ROWSZ; i += 256) {
        int r   = i / ROWSZ;
        int rem = i - r * ROWSZ;
        int x0  = rem / GZ;
        int z   = rem - x0 * GZ;
        float2 g = gsrc[i];
        int o = z * ZSTR + r * PADX + x0;
        sls[o]         = g.x;
        sls[o + AHALF] = g.y;
    }
    __syncthreads();

    int x   = tid << 2;          // 4 px per thread per row
    int x0v = tid >> 1;          // x>>3, constant across the quad
    float txb = (float)(x & 7) * 0.125f;

    size_t rowBase = (size_t)(imgBase + b) * (HDIM * WDIM) + (size_t)(k << 3) * WDIM + x;

    #pragma unroll
    for (int r = 0; r < 8; ++r) {
        size_t pixBase = rowBase + (size_t)r * WDIM;
        float4 v4 = *(const float4*)(img + pixBase);
        float ty = (float)r * 0.125f;
        float wy0 = 1.f - ty, wy1 = ty;

        float vv[4] = {v4.x, v4.y, v4.z, v4.w};
        float rr[4];
        #pragma unroll
        for (int j = 0; j < 4; ++j) {
            float v  = vv[j];
            float fz = fminf(fmaxf(v * 15.0f, 0.0f), 15.0f);
            float zf = floorf(fz);
            int   z0 = (int)zf;
            float tz = fz - zf;
            float tx = txb + (float)j * 0.125f;
            float wx0 = 1.f - tx, wx1 = tx;
            float wz0 = 1.f - tz, wz1 = tz;

            int base = z0 * ZSTR + x0v;        // all 16 reads: base + const offset
            // val reads (bank = x0 % 32, conflict-free)
            float v000 = sls[base];                    // y0 x0 z0
            float v001 = sls[base + ZSTR];             // y0 x0 z1
            float v010 = sls[base + 1];                // y0 x1 z0
            float v011 = sls[base + ZSTR + 1];         // y0 x1 z1
            float v100 = sls[base + PADX];             // y1 x0 z0
            float v101 = sls[base + ZSTR + PADX];      // y1 x0 z1
            float v110 = sls[base + PADX + 1];         // y1 x1 z0
            float v111 = sls[base + ZSTR + PADX + 1];  // y1 x1 z1
            // wt reads
            float w000 = sls[base + AHALF];
            float w001 = sls[base + ZSTR + AHALF];
            float w010 = sls[base + 1 + AHALF];
            float w011 = sls[base + ZSTR + 1 + AHALF];
            float w100 = sls[base + PADX + AHALF];
            float w101 = sls[base + ZSTR + PADX + AHALF];
            float w110 = sls[base + PADX + 1 + AHALF];
            float w111 = sls[base + ZSTR + PADX + 1 + AHALF];

            float ov = 0.f, ow = 0.f, w;
            w = wy0 * wx0 * wz0; ov += w * v000; ow += w * w000;
            w = wy0 * wx0 * wz1; ov += w * v001; ow += w * w001;
            w = wy0 * wx1 * wz0; ov += w * v010; ow += w * w010;
            w = wy0 * wx1 * wz1; ov += w * v011; ow += w * w011;
            w = wy1 * wx0 * wz0; ov += w * v100; ow += w * w100;
            w = wy1 * wx0 * wz1; ov += w * v101; ow += w * w101;
            w = wy1 * wx1 * wz0; ov += w * v110; ow += w * w110;
            w = wy1 * wx1 * wz1; ov += w * v111; ow += w * w111;
            rr[j] = ov / (ow + EPSV);
        }
        float4 r4; r4.x = rr[0]; r4.y = rr[1]; r4.z = rr[2]; r4.w = rr[3];
        *(float4*)(out + pixBase) = r4;
    }
}

extern "C" void kernel_launch(void* const* d_in, const int* in_sizes, int n_in,
                              void* d_out, int out_size, void* d_ws, size_t ws_size,
                              hipStream_t stream)
{
    const float* img = (const float*)d_in[0];
    const float* fs  = (const float*)d_in[2];
    const float* fr  = (const float*)d_in[3];
    float* out = (float*)d_out;

    int nImgTotal = in_sizes[0] / (HDIM * WDIM);   // 12
    size_t perImgBytes = (size_t)CELLS * 2 * sizeof(float);

    int maxChunk = (int)(ws_size / (2 * perImgBytes));
    if (maxChunk < 1) return;
    if (maxChunk > nImgTotal) maxChunk = nImgTotal;

    const int tilesPerDim = (GH + TO - 1) / TO;    // 11

    for (int base = 0; base < nImgTotal; base += maxChunk) {
        int c = nImgTotal - base;
        if (c > maxChunk) c = maxChunk;

        float* A = (float*)d_ws;
        float* B = A + (size_t)c * CELLS * 2;

        int nCols = c * GH * GW;
        int colBlocks = (nCols + 63) / 64;
        splat_gather_kernel<<<colBlocks, 64, 0, stream>>>(img, A, c, base);

        dim3 bgrid(tilesPerDim, tilesPerDim, c);
        blur_fused_kernel<<<bgrid, 256, 0, stream>>>((const float2*)A, (float2*)B, fs, fr);

        dim3 sgrid(HDIM / 8, c);
        slice_rows_kernel<<<sgrid, 256, 0, stream>>>(img, (const float2*)B, out, base);
    }
}